// Round 11
// baseline (278.138 us; speedup 1.0000x reference)
//
#include <hip/hip_runtime.h>
#include <hip/hip_bf16.h>
#include <hip/hip_cooperative_groups.h>

namespace cg = cooperative_groups;

// Capsule dynamic routing — one cooperative dispatch using ALL 256 CUs.
// r10 post-mortem: single 64-block kernel = 110us with 5.6% occupancy and
// ~90% latency stalls; wide dispatches (ksum) hit ~70% HBM peak on this
// machine. Fix: 256 blocks (4 per batch, 512 rows each), grid.sync() at the
// two cross-block reduction points. Epilogues computed redundantly by all
// 4 blocks of a batch (saves syncs). Tile math verbatim r10 (absmax 0.0039).

#define BB 64
#define NN 2048
#define DD 64
#define II 32

typedef __attribute__((ext_vector_type(8)))  short bf16x8;
typedef __attribute__((ext_vector_type(16))) float f32x16;

__device__ __forceinline__ short f2bf(float f) {
    __hip_bfloat16 h = __float2bfloat16(f);
    return *reinterpret_cast<short*>(&h);
}
__device__ __forceinline__ float bf2f(short s) {
    __hip_bfloat16 h = *reinterpret_cast<__hip_bfloat16*>(&s);
    return __bfloat162float(h);
}

// ---------------- cooperative kernel: 256 blocks x 512 threads ----------------
__global__ __launch_bounds__(512) void kco(const float* __restrict__ u,
                                           const float* __restrict__ W,
                                           float* __restrict__ out,
                                           float* __restrict__ sglob,
                                           float* __restrict__ tglob) {
    cg::grid_group grid = cg::this_grid();

    int blk = blockIdx.x;
    int b = blk >> 2, q = blk & 3;          // batch, quarter (512 rows)
    int tid = threadIdx.x;
    int wv = tid >> 6;                      // wave 0..7, owns 64 rows
    int l = tid & 63, h = l >> 5, ln = l & 31;
    int ii = tid >> 4, jj0 = tid & 15;      // epilogue mapping: capsule, dim

    __shared__ unsigned short ush[8][2048];   // per-wave 32-row u tile, bf16 hi
    __shared__ unsigned short usl[8][2048];   // lo plane
    __shared__ float cslab[8][II * 33];       // per-wave c[n][i]
    __shared__ float tlds[II][65];
    __shared__ float wlds[II][68];
    __shared__ float slds[8][DD];
    __shared__ float ssum[DD];
    __shared__ float osh[II][16];

    const float* ubase = u + (size_t)b * NN * DD;
    int rbase = q * 512 + wv * 64;          // this wave's 64 rows

    // ---- phase A: partial s over this block's 512 rows ----
    {
        const float4* up = reinterpret_cast<const float4*>(ubase + (size_t)rbase * DD);
        int r0 = l >> 4, c4 = l & 15;
        float4 a0 = {0.f, 0.f, 0.f, 0.f};
        #pragma unroll
        for (int s = 0; s < 16; ++s) {      // 16 independent loads in flight
            float4 v = up[(s * 4 + r0) * 16 + c4];
            a0.x += v.x; a0.y += v.y; a0.z += v.z; a0.w += v.w;
        }
        #pragma unroll
        for (int off = 16; off <= 32; off <<= 1) {
            a0.x += __shfl_xor(a0.x, off);
            a0.y += __shfl_xor(a0.y, off);
            a0.z += __shfl_xor(a0.z, off);
            a0.w += __shfl_xor(a0.w, off);
        }
        if (l < 16) *reinterpret_cast<float4*>(&slds[wv][l * 4]) = a0;
    }
    __syncthreads();
    if (tid < DD) {
        float a = 0.f;
        #pragma unroll
        for (int wq = 0; wq < 8; ++wq) a += slds[wq][tid];
        sglob[(size_t)blk * DD + tid] = a;
    }
    __threadfence();
    grid.sync();                            // sync 1: s partials visible

    // ---- phase B (all blocks, redundant): s total, o0, l2norm, w~ ----
    if (tid < DD) {
        float a = 0.f;
        #pragma unroll
        for (int q2 = 0; q2 < 4; ++q2) a += sglob[(size_t)(b * 4 + q2) * DD + tid];
        ssum[tid] = a;
    }
    __syncthreads();
    {
        float o = 0.f;
        #pragma unroll 8
        for (int d = 0; d < DD; ++d) o += ssum[d] * W[d * 512 + ii * 16 + jj0];
        o *= (1.0f / 32.0f);
        float ss = o * o;
        #pragma unroll
        for (int off = 8; off >= 1; off >>= 1) ss += __shfl_xor(ss, off, 16);
        osh[ii][jj0] = o / sqrtf(fmaxf(ss, 1e-12f));
    }
    __syncthreads();
    #pragma unroll
    for (int k = 0; k < 4; ++k) {
        int d = jj0 + 16 * k;
        float acc = 0.f;
        #pragma unroll
        for (int j2 = 0; j2 < 16; ++j2)
            acc += W[d * 512 + ii * 16 + j2] * osh[ii][j2];
        wlds[ii][d] = acc;
    }
    __syncthreads();

    // ---- routing iterations ----
    for (int it = 0; it < 2; ++it) {
        bf16x8 Aw[4];
        #pragma unroll
        for (int kt = 0; kt < 4; ++kt) {
            const float* p = &wlds[ln][kt * 16 + h * 8];
            #pragma unroll
            for (int e2 = 0; e2 < 8; ++e2) Aw[kt][e2] = f2bf(p[e2]);
        }
        f32x16 G0, G1;
        #pragma unroll
        for (int r = 0; r < 16; ++r) { G0[r] = 0.f; G1[r] = 0.f; }

        #pragma unroll
        for (int tt = 0; tt < 2; ++tt) {    // 2 tiles of 32 rows per wave
            int n0 = rbase + tt * 32;
            bf16x8 Bh[4], Bl[4];
            float4 v0[4], v1[4];
            #pragma unroll
            for (int kt = 0; kt < 4; ++kt) {    // issue all 8 loads first
                const float4* p = reinterpret_cast<const float4*>(
                    ubase + (size_t)(n0 + ln) * DD + kt * 16 + h * 8);
                v0[kt] = p[0]; v1[kt] = p[1];
            }
            #pragma unroll
            for (int kt = 0; kt < 4; ++kt) {
                float vf[8] = {v0[kt].x, v0[kt].y, v0[kt].z, v0[kt].w,
                               v1[kt].x, v1[kt].y, v1[kt].z, v1[kt].w};
                #pragma unroll
                for (int e2 = 0; e2 < 8; ++e2) {
                    short hi = f2bf(vf[e2]);
                    Bh[kt][e2] = hi;
                    Bl[kt][e2] = f2bf(vf[e2] - bf2f(hi));
                }
                int d0 = kt * 16 + h * 8;
                int idx = ln * 64 + (d0 ^ ((ln & 7) << 3));
                *reinterpret_cast<bf16x8*>(&ush[wv][idx]) = Bh[kt];
                *reinterpret_cast<bf16x8*>(&usl[wv][idx]) = Bl[kt];
            }
            f32x16 S;
            #pragma unroll
            for (int r = 0; r < 16; ++r) S[r] = 0.f;
            #pragma unroll
            for (int kt = 0; kt < 4; ++kt)
                S = __builtin_amdgcn_mfma_f32_32x32x16_bf16(Aw[kt], Bh[kt], S, 0, 0, 0);
            float m = S[0];
            #pragma unroll
            for (int r = 1; r < 16; ++r) m = fmaxf(m, S[r]);
            m = fmaxf(m, __shfl_xor(m, 32));
            float sum = 0.f, e[16];
            #pragma unroll
            for (int r = 0; r < 16; ++r) { e[r] = __expf(S[r] - m); sum += e[r]; }
            sum += __shfl_xor(sum, 32);
            float inv = 1.f / sum;
            #pragma unroll
            for (int r = 0; r < 16; ++r) {
                int irow = (r & 3) + 8 * (r >> 2) + 4 * h;
                cslab[wv][ln * 33 + irow] = e[r] * inv;     // c[n=ln][i]
            }
            #pragma unroll
            for (int t2 = 0; t2 < 2; ++t2) {
                bf16x8 Ah, Al;
                #pragma unroll
                for (int qq = 0; qq < 8; ++qq) {
                    float cv = cslab[wv][(t2 * 16 + h * 8 + qq) * 33 + ln];
                    short hi = f2bf(cv);
                    Ah[qq] = hi;
                    Al[qq] = f2bf(cv - bf2f(hi));
                }
                #pragma unroll
                for (int Nt = 0; Nt < 2; ++Nt) {
                    bf16x8 B2h, B2l;
                    #pragma unroll
                    for (int qq = 0; qq < 8; ++qq) {
                        int row = t2 * 16 + h * 8 + qq;
                        int idx = row * 64 + ((Nt * 32 + ln) ^ ((row & 7) << 3));
                        B2h[qq] = (short)ush[wv][idx];
                        B2l[qq] = (short)usl[wv][idx];
                    }
                    if (Nt == 0) {
                        G0 = __builtin_amdgcn_mfma_f32_32x32x16_bf16(Ah, B2h, G0, 0, 0, 0);
                        G0 = __builtin_amdgcn_mfma_f32_32x32x16_bf16(Al, B2h, G0, 0, 0, 0);
                        G0 = __builtin_amdgcn_mfma_f32_32x32x16_bf16(Ah, B2l, G0, 0, 0, 0);
                    } else {
                        G1 = __builtin_amdgcn_mfma_f32_32x32x16_bf16(Ah, B2h, G1, 0, 0, 0);
                        G1 = __builtin_amdgcn_mfma_f32_32x32x16_bf16(Al, B2h, G1, 0, 0, 0);
                        G1 = __builtin_amdgcn_mfma_f32_32x32x16_bf16(Ah, B2l, G1, 0, 0, 0);
                    }
                }
            }
        }

        // block-local t reduce -> tglob partial
        for (int k = tid; k < II * 65; k += 512) (&tlds[0][0])[k] = 0.f;
        __syncthreads();
        #pragma unroll
        for (int r = 0; r < 16; ++r) {
            int irow = (r & 3) + 8 * (r >> 2) + 4 * h;
            atomicAdd(&tlds[irow][ln],      G0[r]);
            atomicAdd(&tlds[irow][32 + ln], G1[r]);
        }
        __syncthreads();
        for (int k = tid; k < II * DD; k += 512)
            tglob[(size_t)blk * (II * DD) + k] = tlds[k >> 6][k & 63];
        __threadfence();
        grid.sync();                        // sync 2/3: t partials visible

        // epilogue (all blocks, redundant): t total, o, l2norm/squash
        for (int k = tid; k < II * DD; k += 512) {
            float a = 0.f;
            #pragma unroll
            for (int q2 = 0; q2 < 4; ++q2)
                a += tglob[(size_t)(b * 4 + q2) * (II * DD) + k];
            tlds[k >> 6][k & 63] = a;
        }
        __syncthreads();
        float o = 0.f;
        #pragma unroll 8
        for (int d = 0; d < DD; ++d) o += tlds[ii][d] * W[d * 512 + ii * 16 + jj0];
        float ss = o * o;
        #pragma unroll
        for (int off = 8; off >= 1; off >>= 1) ss += __shfl_xor(ss, off, 16);

        if (it == 0) {
            float ov = o / sqrtf(fmaxf(ss, 1e-12f));     // tf l2_normalize
            osh[ii][jj0] = ov;
            __syncthreads();
            #pragma unroll
            for (int k = 0; k < 4; ++k) {
                int d = jj0 + 16 * k;
                float acc = 0.f;
                #pragma unroll
                for (int j2 = 0; j2 < 16; ++j2)
                    acc += W[d * 512 + ii * 16 + j2] * osh[ii][j2];
                wlds[ii][d] = acc;
            }
            __syncthreads();
        } else if (q == 0) {
            float s2 = ss + 1e-7f;                        // K.epsilon
            float scale = sqrtf(s2) / (0.5f + s2);        // squash
            out[(size_t)b * 512 + tid] = scale * o;
        }
    }
}

// ---------------- fallback: r10's proven single-dispatch kernel ----------------
__global__ __launch_bounds__(512) void kall(const float* __restrict__ u,
                                            const float* __restrict__ W,
                                            float* __restrict__ out) {
    int b = blockIdx.x;
    int tid = threadIdx.x;
    int wv = tid >> 6;
    int l = tid & 63, h = l >> 5, ln = l & 31;
    int ii = tid >> 4, jj0 = tid & 15;

    __shared__ unsigned short ush[8][2048];
    __shared__ unsigned short usl[8][2048];
    __shared__ float cslab[8][II * 33];
    __shared__ float tlds[II][65];
    __shared__ float wlds[II][68];
    __shared__ float slds[8][DD];
    __shared__ float ssum[DD];
    __shared__ float osh[II][16];

    const float* ubase = u + (size_t)b * NN * DD;

    {
        const float4* up = reinterpret_cast<const float4*>(ubase + (size_t)wv * 256 * DD);
        int r0 = l >> 4, c4 = l & 15;
        float4 a0 = {0.f, 0.f, 0.f, 0.f};
        #pragma unroll 8
        for (int s = 0; s < 64; ++s) {
            float4 v = up[(s * 4 + r0) * 16 + c4];
            a0.x += v.x; a0.y += v.y; a0.z += v.z; a0.w += v.w;
        }
        #pragma unroll
        for (int off = 16; off <= 32; off <<= 1) {
            a0.x += __shfl_xor(a0.x, off);
            a0.y += __shfl_xor(a0.y, off);
            a0.z += __shfl_xor(a0.z, off);
            a0.w += __shfl_xor(a0.w, off);
        }
        if (l < 16) *reinterpret_cast<float4*>(&slds[wv][l * 4]) = a0;
    }
    for (int k = tid; k < II * 65; k += 512) (&tlds[0][0])[k] = 0.f;
    __syncthreads();

    if (tid < DD) {
        float a = 0.f;
        #pragma unroll
        for (int wq = 0; wq < 8; ++wq) a += slds[wq][tid];
        ssum[tid] = a;
    }
    __syncthreads();
    {
        float o = 0.f;
        #pragma unroll 8
        for (int d = 0; d < DD; ++d) o += ssum[d] * W[d * 512 + ii * 16 + jj0];
        o *= (1.0f / 32.0f);
        float ss = o * o;
        #pragma unroll
        for (int off = 8; off >= 1; off >>= 1) ss += __shfl_xor(ss, off, 16);
        osh[ii][jj0] = o / sqrtf(fmaxf(ss, 1e-12f));
    }
    __syncthreads();
    #pragma unroll
    for (int k = 0; k < 4; ++k) {
        int d = jj0 + 16 * k;
        float acc = 0.f;
        #pragma unroll
        for (int j2 = 0; j2 < 16; ++j2)
            acc += W[d * 512 + ii * 16 + j2] * osh[ii][j2];
        wlds[ii][d] = acc;
    }
    __syncthreads();

    for (int it = 0; it < 2; ++it) {
        bf16x8 Aw[4];
        #pragma unroll
        for (int kt = 0; kt < 4; ++kt) {
            const float* p = &wlds[ln][kt * 16 + h * 8];
            #pragma unroll
            for (int e2 = 0; e2 < 8; ++e2) Aw[kt][e2] = f2bf(p[e2]);
        }
        f32x16 G0, G1;
        #pragma unroll
        for (int r = 0; r < 16; ++r) { G0[r] = 0.f; G1[r] = 0.f; }

        for (int tt = 0; tt < 8; ++tt) {
            int n0 = wv * 256 + tt * 32;
            bf16x8 Bh[4], Bl[4];
            #pragma unroll
            for (int kt = 0; kt < 4; ++kt) {
                const float4* p = reinterpret_cast<const float4*>(
                    ubase + (size_t)(n0 + ln) * DD + kt * 16 + h * 8);
                float4 v0 = p[0], v1 = p[1];
                float vf[8] = {v0.x, v0.y, v0.z, v0.w, v1.x, v1.y, v1.z, v1.w};
                #pragma unroll
                for (int e2 = 0; e2 < 8; ++e2) {
                    short hi = f2bf(vf[e2]);
                    Bh[kt][e2] = hi;
                    Bl[kt][e2] = f2bf(vf[e2] - bf2f(hi));
                }
                int d0 = kt * 16 + h * 8;
                int idx = ln * 64 + (d0 ^ ((ln & 7) << 3));
                *reinterpret_cast<bf16x8*>(&ush[wv][idx]) = Bh[kt];
                *reinterpret_cast<bf16x8*>(&usl[wv][idx]) = Bl[kt];
            }
            f32x16 S;
            #pragma unroll
            for (int r = 0; r < 16; ++r) S[r] = 0.f;
            #pragma unroll
            for (int kt = 0; kt < 4; ++kt)
                S = __builtin_amdgcn_mfma_f32_32x32x16_bf16(Aw[kt], Bh[kt], S, 0, 0, 0);
            float m = S[0];
            #pragma unroll
            for (int r = 1; r < 16; ++r) m = fmaxf(m, S[r]);
            m = fmaxf(m, __shfl_xor(m, 32));
            float sum = 0.f, e[16];
            #pragma unroll
            for (int r = 0; r < 16; ++r) { e[r] = __expf(S[r] - m); sum += e[r]; }
            sum += __shfl_xor(sum, 32);
            float inv = 1.f / sum;
            #pragma unroll
            for (int r = 0; r < 16; ++r) {
                int irow = (r & 3) + 8 * (r >> 2) + 4 * h;
                cslab[wv][ln * 33 + irow] = e[r] * inv;
            }
            #pragma unroll
            for (int t2 = 0; t2 < 2; ++t2) {
                bf16x8 Ah, Al;
                #pragma unroll
                for (int qq = 0; qq < 8; ++qq) {
                    float cv = cslab[wv][(t2 * 16 + h * 8 + qq) * 33 + ln];
                    short hi = f2bf(cv);
                    Ah[qq] = hi;
                    Al[qq] = f2bf(cv - bf2f(hi));
                }
                #pragma unroll
                for (int Nt = 0; Nt < 2; ++Nt) {
                    bf16x8 B2h, B2l;
                    #pragma unroll
                    for (int qq = 0; qq < 8; ++qq) {
                        int row = t2 * 16 + h * 8 + qq;
                        int idx = row * 64 + ((Nt * 32 + ln) ^ ((row & 7) << 3));
                        B2h[qq] = (short)ush[wv][idx];
                        B2l[qq] = (short)usl[wv][idx];
                    }
                    if (Nt == 0) {
                        G0 = __builtin_amdgcn_mfma_f32_32x32x16_bf16(Ah, B2h, G0, 0, 0, 0);
                        G0 = __builtin_amdgcn_mfma_f32_32x32x16_bf16(Al, B2h, G0, 0, 0, 0);
                        G0 = __builtin_amdgcn_mfma_f32_32x32x16_bf16(Ah, B2l, G0, 0, 0, 0);
                    } else {
                        G1 = __builtin_amdgcn_mfma_f32_32x32x16_bf16(Ah, B2h, G1, 0, 0, 0);
                        G1 = __builtin_amdgcn_mfma_f32_32x32x16_bf16(Al, B2h, G1, 0, 0, 0);
                        G1 = __builtin_amdgcn_mfma_f32_32x32x16_bf16(Ah, B2l, G1, 0, 0, 0);
                    }
                }
            }
        }
        #pragma unroll
        for (int r = 0; r < 16; ++r) {
            int irow = (r & 3) + 8 * (r >> 2) + 4 * h;
            atomicAdd(&tlds[irow][ln],      G0[r]);
            atomicAdd(&tlds[irow][32 + ln], G1[r]);
        }
        __syncthreads();

        float o = 0.f;
        #pragma unroll 8
        for (int d = 0; d < DD; ++d) o += tlds[ii][d] * W[d * 512 + ii * 16 + jj0];
        float ss = o * o;
        #pragma unroll
        for (int off = 8; off >= 1; off >>= 1) ss += __shfl_xor(ss, off, 16);

        if (it == 0) {
            float ov = o / sqrtf(fmaxf(ss, 1e-12f));
            __syncthreads();
            osh[ii][jj0] = ov;
            __syncthreads();
            #pragma unroll
            for (int k = 0; k < 4; ++k) {
                int d = jj0 + 16 * k;
                float acc = 0.f;
                #pragma unroll
                for (int j2 = 0; j2 < 16; ++j2)
                    acc += W[d * 512 + ii * 16 + j2] * osh[ii][j2];
                wlds[ii][d] = acc;
            }
            for (int k = tid; k < II * 65; k += 512) (&tlds[0][0])[k] = 0.f;
            __syncthreads();
        } else {
            float s2 = ss + 1e-7f;
            float scale = sqrtf(s2) / (0.5f + s2);
            out[(size_t)b * 512 + tid] = scale * o;
        }
    }
}

extern "C" void kernel_launch(void* const* d_in, const int* in_sizes, int n_in,
                              void* d_out, int out_size, void* d_ws, size_t ws_size,
                              hipStream_t stream) {
    const float* u = (const float*)d_in[0];     // (64, 2048, 64)
    const float* W = (const float*)d_in[1];     // (1, 64, 512)
    float* out = (float*)d_out;                 // (64, 32, 16)
    float* ws = (float*)d_ws;

    float* sglob = ws;                          // 256*64 floats   (64 KB)
    float* tglob = ws + 256 * DD;               // 256*2048 floats (2 MB)

    void* args[] = {(void*)&u, (void*)&W, (void*)&out, (void*)&sglob, (void*)&tglob};
    hipError_t e = hipLaunchCooperativeKernel((const void*)kco, dim3(256), dim3(512),
                                              args, 0, stream);
    if (e != hipSuccess) {
        // deterministic per-environment fallback: r10's proven kernel
        kall<<<BB, 512, 0, stream>>>(u, W, out);
    }
}